// Round 1
// baseline (724.916 us; speedup 1.0000x reference)
//
#include <hip/hip_runtime.h>

// MaskedBatchNorm2d: B=16, C=64, W=256, H=256, fp32.
// Identity: masked-out locations are exactly +/-0 in all channels, so masked
// per-channel sums == full sums and out = x*inv[c] everywhere (exact-
// cancellation "dirty" locations handled by a ~never-taken fixup path).
//
// R1: global atomics removed (823us -> 594us).
// R2 (this round): pass1 barrier/occupancy fix (8 blocks/CU, 2-tile groups,
// 4 barrier pairs instead of 8), finalize parallelized 4x (1024 threads),
// fixup folded into pass2 (own-range patch), nontemporal out stores.

#define NB 16
#define CB 64
#define WH 65536               // W*H
#define TILE 256               // locations per tile (block-wide)
#define NTILES (NB * WH / TILE)  // 4096
#define GRID1 1024
#define TPT (NTILES / GRID1)   // 4 tiles per block
#define DIRTY_CAP 512
#define EPS 0.001f

typedef float f32x4 __attribute__((ext_vector_type(4)));

// ws layout (float units):
//  [0 .. 131071]        sqPart[GRID1][128]  (S row 0..63, Q row 64..127) - 512 KB
//  [131072 .. 147455]   nPart[GRID1][16]    (uint)                       -  64 KB
//  [147456]             dirtyCnt (uint, zeroed by memset)
//  [147520 .. 147583]   inv[64]
//  [147584 .. 147599]   padArr[16] (int)
//  [147600 .. 148111]   dirtyLoc[DIRTY_CAP] (int)

__global__ __launch_bounds__(256, 8)
void mbn_pass1(const float* __restrict__ x, float* __restrict__ sqPart,
               unsigned* __restrict__ nPart, unsigned* __restrict__ dirtyCnt,
               int* __restrict__ dirtyLoc) {
    // 2 tile-slots x 4 waves x 256 locations; 16 KB total -> 8 blocks/CU fits
    __shared__ float lds_s[2][4][TILE];
    __shared__ float lds_a[2][4][TILE];
    __shared__ unsigned cnt_lds[16];
    const int tid  = threadIdx.x;
    const int wave = tid >> 6;
    const int lane = tid & 63;
    if (tid < 16) cnt_lds[tid] = 0;

    float sAcc[16], qAcc[16];
#pragma unroll
    for (int j = 0; j < 16; ++j) { sAcc[j] = 0.f; qAcc[j] = 0.f; }
    __syncthreads();

    for (int g = 0; g < 2; ++g) {
        // ---- load/accumulate phase: 2 tiles, 32 loads, no barrier between ----
#pragma unroll
        for (int sub = 0; sub < 2; ++sub) {
            const int tile = blockIdx.x + (g * 2 + sub) * GRID1;
            const int b    = tile >> 8;                 // 256 tiles per batch
            const int whb  = (tile & 255) * TILE;
            const float* base = x + (((size_t)(b * 64 + wave * 16)) << 16) + whb + lane * 4;

            float sp0 = 0.f, sp1 = 0.f, sp2 = 0.f, sp3 = 0.f;
            float aa0 = 0.f, aa1 = 0.f, aa2 = 0.f, aa3 = 0.f;
#pragma unroll
            for (int j = 0; j < 16; ++j) {
                float4 v = *(const float4*)(base + ((size_t)j << 16));
                sp0 += v.x; sp1 += v.y; sp2 += v.z; sp3 += v.w;
                aa0 += fabsf(v.x); aa1 += fabsf(v.y); aa2 += fabsf(v.z); aa3 += fabsf(v.w);
                sAcc[j] += (v.x + v.y) + (v.z + v.w);
                qAcc[j] = fmaf(v.x, v.x, qAcc[j]);
                qAcc[j] = fmaf(v.y, v.y, qAcc[j]);
                qAcc[j] = fmaf(v.z, v.z, qAcc[j]);
                qAcc[j] = fmaf(v.w, v.w, qAcc[j]);
            }
            *(float4*)&lds_s[sub][wave][lane * 4] = make_float4(sp0, sp1, sp2, sp3);
            *(float4*)&lds_a[sub][wave][lane * 4] = make_float4(aa0, aa1, aa2, aa3);
        }
        __syncthreads();

        // ---- combine phase: thread t owns location t of each tile ----
#pragma unroll
        for (int sub = 0; sub < 2; ++sub) {
            const int tile = blockIdx.x + (g * 2 + sub) * GRID1;
            const int b    = tile >> 8;
            float s = lds_s[sub][0][tid] + lds_s[sub][1][tid] + lds_s[sub][2][tid] + lds_s[sub][3][tid];
            float a = lds_a[sub][0][tid] + lds_a[sub][1][tid] + lds_a[sub][2][tid] + lds_a[sub][3][tid];
            bool mask = (s != 0.0f);
            unsigned long long bal = __ballot(mask);
            if (lane == 0) atomicAdd(&cnt_lds[b], (unsigned)__popcll(bal));  // LDS atomic
            if (!mask && a != 0.0f) {                   // exact cancellation: ~never
                unsigned idx = atomicAdd(dirtyCnt, 1u);
                if (idx < DIRTY_CAP) dirtyLoc[idx] = (b << 16) | ((tile & 255) * TILE + tid);
            }
        }
        __syncthreads();
    }

    // wave-reduce register accumulators; plain stores to this block's ws row
#pragma unroll
    for (int j = 0; j < 16; ++j) {
        float sv = sAcc[j], qv = qAcc[j];
        for (int off = 32; off; off >>= 1) {
            sv += __shfl_xor(sv, off);
            qv += __shfl_xor(qv, off);
        }
        if (lane == 0) {
            sqPart[blockIdx.x * 128 + wave * 16 + j]      = sv;
            sqPart[blockIdx.x * 128 + 64 + wave * 16 + j] = qv;
        }
    }
    if (tid < 16) nPart[blockIdx.x * 16 + tid] = cnt_lds[tid];
}

__global__ __launch_bounds__(1024)
void mbn_finalize(const float* __restrict__ x, const float* __restrict__ sqPart,
                  const unsigned* __restrict__ nPart,
                  const unsigned* __restrict__ dirtyCnt, const int* __restrict__ dirtyLoc,
                  float* __restrict__ inv, int* __restrict__ padOut) {
    __shared__ float red[1024];
    __shared__ float sq[128];
    __shared__ unsigned npar[16][16];
    __shared__ unsigned ntot[16];
    const int t = threadIdx.x;            // 1024 threads
    const int col = t & 127, grp = t >> 7;  // 8 row-groups of 128 rows

    // coalesced reduce of sqPart: thread t sums column col over its 128 rows
    float acc = 0.f;
    const float* p = sqPart + (size_t)grp * 128 * 128 + col;
#pragma unroll 8
    for (int r = 0; r < 128; ++r) acc += p[(size_t)r * 128];
    red[t] = acc;

    if (t < 256) {                         // mask counts: 16 groups x 16 batches
        const int b = t & 15, g2 = t >> 4;
        unsigned s = 0;
        const unsigned* np = nPart + g2 * 64 * 16 + b;
#pragma unroll 8
        for (int r = 0; r < 64; ++r) s += np[r * 16];
        npar[g2][b] = s;
    }
    __syncthreads();
    if (t < 128) {
        float v = 0.f;
#pragma unroll
        for (int g2 = 0; g2 < 8; ++g2) v += red[g2 * 128 + t];
        sq[t] = v;
    }
    if (t < 16) {
        unsigned v = 0;
#pragma unroll
        for (int g2 = 0; g2 < 16; ++g2) v += npar[g2][t];
        ntot[t] = v;
    }
    __syncthreads();

    if (t < 64) {
        const int c = t;
        unsigned nmax = 0;
#pragma unroll
        for (int b = 0; b < NB; ++b) { unsigned nb = ntot[b]; nmax = nb > nmax ? nb : nmax; }
        const float total = (float)(16u * nmax);   // B*Nmax, exact in fp32

        float s = sq[c], q = sq[64 + c];
        // dirty corrections (exclude exact-cancellation locations) — ~never runs
        unsigned cnt = *dirtyCnt; if (cnt > DIRTY_CAP) cnt = DIRTY_CAP;
        for (unsigned i = 0; i < cnt; ++i) {
            int loc = dirtyLoc[i];
            int b = loc >> 16, wh = loc & 65535;
            float v = x[(((size_t)(b * 64 + c)) << 16) + wh];
            s -= v; q -= v * v;
        }
        float p1 = 0.f, p2 = 0.f;
#pragma unroll
        for (int b = 0; b < NB; ++b) {
            float padf = (float)(nmax - ntot[b]);
            float v00  = x[((size_t)(b * 64 + c)) << 16];
            p1 = fmaf(padf, v00, p1);
            p2 = fmaf(padf, v00 * v00, p2);
            if (c == 0) padOut[b] = (int)(nmax - ntot[b]);
        }
        float mean = (s + p1) / total;
        float var  = (q + p2) / total - mean * mean;   // algebraic identity w/ ref
        inv[c] = 1.0f / sqrtf(var + EPS);
    }
}

__global__ __launch_bounds__(256)
void mbn_pass2(const float* __restrict__ x, float* __restrict__ out,
               const float* __restrict__ inv, const unsigned* __restrict__ dirtyCnt,
               const int* __restrict__ dirtyLoc, const int* __restrict__ padArr) {
    // 8192 blocks x 2048 float4: each block's chunk lies in ONE channel plane
    const int blk = blockIdx.x;
    const float sc = inv[(blk >> 3) & 63];             // 8 blocks per plane
    const f32x4* x4 = (const f32x4*)x;
    f32x4* out4 = (f32x4*)out;
    const size_t base = (size_t)blk * 2048 + threadIdx.x;
#pragma unroll
    for (int k = 0; k < 8; ++k) {
        size_t i = base + (size_t)k * 256;
        f32x4 v = x4[i];
        v *= sc;
        __builtin_nontemporal_store(v, &out4[i]);      // out never re-read
    }

    // folded fixup: each block patches only its OWN float range (no cross-
    // block ordering needed). dirtyCnt == 0 in practice -> uniform early out.
    unsigned cnt = *dirtyCnt;
    if (cnt != 0) {
        __syncthreads();                               // order NT stores vs patch
        if (threadIdx.x == 0) {
            if (cnt > DIRTY_CAP) cnt = DIRTY_CAP;
            const int bb = blk >> 9, cc = (blk >> 3) & 63, seg = blk & 7;
            const int lo = seg * 8192, hi = lo + 8192;
            for (unsigned i = 0; i < cnt; ++i) {
                int loc = dirtyLoc[i];
                int b = loc >> 16, wh = loc & 65535;
                if (b != bb || wh < lo || wh >= hi) continue;
                if (wh == 0 && padArr[b] > 0) continue;   // (0,0) override wins
                size_t idx = (((size_t)(b * 64 + cc)) << 16) + wh;
                out[idx] = x[idx];                        // m=0 w/ nonzero x: out = x
            }
        }
    }
}

extern "C" void kernel_launch(void* const* d_in, const int* in_sizes, int n_in,
                              void* d_out, int out_size, void* d_ws, size_t ws_size,
                              hipStream_t stream) {
    const float* x = (const float*)d_in[0];
    float* out = (float*)d_out;
    float* wsf = (float*)d_ws;

    float*    sqPart   = wsf;
    unsigned* nPart    = (unsigned*)(wsf + 131072);
    unsigned* dirtyCnt = (unsigned*)(wsf + 147456);
    float*    inv      = wsf + 147520;
    int*      padArr   = (int*)(wsf + 147584);
    int*      dirtyLoc = (int*)(wsf + 147600);

    // only dirtyCnt needs zeroing (partials are written unconditionally)
    hipMemsetAsync((char*)d_ws + 147456 * 4, 0, 64, stream);

    mbn_pass1<<<GRID1, 256, 0, stream>>>(x, sqPart, nPart, dirtyCnt, dirtyLoc);
    mbn_finalize<<<1, 1024, 0, stream>>>(x, sqPart, nPart, dirtyCnt, dirtyLoc, inv, padArr);
    mbn_pass2<<<8192, 256, 0, stream>>>(x, out, inv, dirtyCnt, dirtyLoc, padArr);
}

// Round 2
// 564.054 us; speedup vs baseline: 1.2852x; 1.2852x over previous
//
#include <hip/hip_runtime.h>

// MaskedBatchNorm2d: B=16, C=64, W=256, H=256, fp32.
// Identity: masked-out locations are exactly +/-0 in all channels, so masked
// per-channel sums == full sums and out = x*inv[c] everywhere (exact-
// cancellation "dirty" locations handled by a ~never-taken fixup path).
//
// R1: global atomics removed (823us -> 594us).
// R2 FAILED: __launch_bounds__(256,8) spilled sAcc[16]/qAcc[16] (VGPR 64->32,
//            +500MB scratch HBM traffic, pass1 174->319us).
// R3 (this round): occupancy without spill - 512-thread blocks, 8 waves x
// 8 channels each -> acc arrays 16 regs (was 32), ~56 VGPR total fits the
// 64-reg budget of (512,8) -> 32 waves/CU (was 16 at 41% occ). Keep R2's
// 1024-thread finalize and pass2 (NT stores + folded fixup), both verified.

#define NB 16
#define CB 64
#define WH 65536               // W*H
#define TILE 256               // locations per tile (block-wide)
#define NTILES (NB * WH / TILE)  // 4096
#define GRID1 1024
#define TPT (NTILES / GRID1)   // 4 tiles per block
#define DIRTY_CAP 512
#define EPS 0.001f

typedef float f32x4 __attribute__((ext_vector_type(4)));

// ws layout (float units):
//  [0 .. 131071]        sqPart[GRID1][128]  (S row 0..63, Q row 64..127) - 512 KB
//  [131072 .. 147455]   nPart[GRID1][16]    (uint)                       -  64 KB
//  [147456]             dirtyCnt (uint, zeroed by memset)
//  [147520 .. 147583]   inv[64]
//  [147584 .. 147599]   padArr[16] (int)
//  [147600 .. 148111]   dirtyLoc[DIRTY_CAP] (int)

__global__ __launch_bounds__(512, 8)
void mbn_pass1(const float* __restrict__ x, float* __restrict__ sqPart,
               unsigned* __restrict__ nPart, unsigned* __restrict__ dirtyCnt,
               int* __restrict__ dirtyLoc) {
    // 8 waves x 8 channels each. LDS: 8 partial rows x 256 loc x {s,a} = 16KB.
    __shared__ float lds_s[8][TILE];
    __shared__ float lds_a[8][TILE];
    __shared__ unsigned cnt_lds[16];
    const int tid  = threadIdx.x;       // 0..511
    const int wave = tid >> 6;          // 0..7
    const int lane = tid & 63;
    if (tid < 16) cnt_lds[tid] = 0;

    float sAcc[8], qAcc[8];             // per-channel S/Q for this wave's 8 ch
#pragma unroll
    for (int j = 0; j < 8; ++j) { sAcc[j] = 0.f; qAcc[j] = 0.f; }
    __syncthreads();

    for (int tt = 0; tt < TPT; ++tt) {
        const int tile = blockIdx.x + tt * GRID1;
        const int b    = tile >> 8;                 // 256 tiles per batch
        const int whb  = (tile & 255) * TILE;
        const float* base = x + (((size_t)(b * 64 + wave * 8)) << 16) + whb + lane * 4;

        float sp0 = 0.f, sp1 = 0.f, sp2 = 0.f, sp3 = 0.f;
        float aa0 = 0.f, aa1 = 0.f, aa2 = 0.f, aa3 = 0.f;
#pragma unroll
        for (int j = 0; j < 8; ++j) {
            float4 v = *(const float4*)(base + ((size_t)j << 16));
            sp0 += v.x; sp1 += v.y; sp2 += v.z; sp3 += v.w;
            aa0 += fabsf(v.x); aa1 += fabsf(v.y); aa2 += fabsf(v.z); aa3 += fabsf(v.w);
            sAcc[j] += (v.x + v.y) + (v.z + v.w);
            qAcc[j] = fmaf(v.x, v.x, qAcc[j]);
            qAcc[j] = fmaf(v.y, v.y, qAcc[j]);
            qAcc[j] = fmaf(v.z, v.z, qAcc[j]);
            qAcc[j] = fmaf(v.w, v.w, qAcc[j]);
        }
        *(float4*)&lds_s[wave][lane * 4] = make_float4(sp0, sp1, sp2, sp3);
        *(float4*)&lds_a[wave][lane * 4] = make_float4(aa0, aa1, aa2, aa3);
        __syncthreads();

        // combine: thread t (t<256) owns location t of the tile
        if (tid < TILE) {
            float s = lds_s[0][tid] + lds_s[1][tid] + lds_s[2][tid] + lds_s[3][tid]
                    + lds_s[4][tid] + lds_s[5][tid] + lds_s[6][tid] + lds_s[7][tid];
            float a = lds_a[0][tid] + lds_a[1][tid] + lds_a[2][tid] + lds_a[3][tid]
                    + lds_a[4][tid] + lds_a[5][tid] + lds_a[6][tid] + lds_a[7][tid];
            bool mask = (s != 0.0f);
            unsigned long long bal = __ballot(mask);
            if (lane == 0) atomicAdd(&cnt_lds[b], (unsigned)__popcll(bal));  // LDS atomic
            if (!mask && a != 0.0f) {                   // exact cancellation: ~never
                unsigned idx = atomicAdd(dirtyCnt, 1u);
                if (idx < DIRTY_CAP) dirtyLoc[idx] = (b << 16) | (whb + tid);
            }
        }
        __syncthreads();
    }

    // wave-reduce register accumulators; plain stores to this block's ws row
#pragma unroll
    for (int j = 0; j < 8; ++j) {
        float sv = sAcc[j], qv = qAcc[j];
        for (int off = 32; off; off >>= 1) {
            sv += __shfl_xor(sv, off);
            qv += __shfl_xor(qv, off);
        }
        if (lane == 0) {
            sqPart[blockIdx.x * 128 + wave * 8 + j]      = sv;   // S at col c
            sqPart[blockIdx.x * 128 + 64 + wave * 8 + j] = qv;   // Q at 64+c
        }
    }
    if (tid < 16) nPart[blockIdx.x * 16 + tid] = cnt_lds[tid];
}

__global__ __launch_bounds__(1024)
void mbn_finalize(const float* __restrict__ x, const float* __restrict__ sqPart,
                  const unsigned* __restrict__ nPart,
                  const unsigned* __restrict__ dirtyCnt, const int* __restrict__ dirtyLoc,
                  float* __restrict__ inv, int* __restrict__ padOut) {
    __shared__ float red[1024];
    __shared__ float sq[128];
    __shared__ unsigned npar[16][16];
    __shared__ unsigned ntot[16];
    const int t = threadIdx.x;            // 1024 threads
    const int col = t & 127, grp = t >> 7;  // 8 row-groups of 128 rows

    // coalesced reduce of sqPart: thread t sums column col over its 128 rows
    float acc = 0.f;
    const float* p = sqPart + (size_t)grp * 128 * 128 + col;
#pragma unroll 8
    for (int r = 0; r < 128; ++r) acc += p[(size_t)r * 128];
    red[t] = acc;

    if (t < 256) {                         // mask counts: 16 groups x 16 batches
        const int b = t & 15, g2 = t >> 4;
        unsigned s = 0;
        const unsigned* np = nPart + g2 * 64 * 16 + b;
#pragma unroll 8
        for (int r = 0; r < 64; ++r) s += np[r * 16];
        npar[g2][b] = s;
    }
    __syncthreads();
    if (t < 128) {
        float v = 0.f;
#pragma unroll
        for (int g2 = 0; g2 < 8; ++g2) v += red[g2 * 128 + t];
        sq[t] = v;
    }
    if (t < 16) {
        unsigned v = 0;
#pragma unroll
        for (int g2 = 0; g2 < 16; ++g2) v += npar[g2][t];
        ntot[t] = v;
    }
    __syncthreads();

    if (t < 64) {
        const int c = t;
        unsigned nmax = 0;
#pragma unroll
        for (int b = 0; b < NB; ++b) { unsigned nb = ntot[b]; nmax = nb > nmax ? nb : nmax; }
        const float total = (float)(16u * nmax);   // B*Nmax, exact in fp32

        float s = sq[c], q = sq[64 + c];
        // dirty corrections (exclude exact-cancellation locations) — ~never runs
        unsigned cnt = *dirtyCnt; if (cnt > DIRTY_CAP) cnt = DIRTY_CAP;
        for (unsigned i = 0; i < cnt; ++i) {
            int loc = dirtyLoc[i];
            int b = loc >> 16, wh = loc & 65535;
            float v = x[(((size_t)(b * 64 + c)) << 16) + wh];
            s -= v; q -= v * v;
        }
        float p1 = 0.f, p2 = 0.f;
#pragma unroll
        for (int b = 0; b < NB; ++b) {
            float padf = (float)(nmax - ntot[b]);
            float v00  = x[((size_t)(b * 64 + c)) << 16];
            p1 = fmaf(padf, v00, p1);
            p2 = fmaf(padf, v00 * v00, p2);
            if (c == 0) padOut[b] = (int)(nmax - ntot[b]);
        }
        float mean = (s + p1) / total;
        float var  = (q + p2) / total - mean * mean;   // algebraic identity w/ ref
        inv[c] = 1.0f / sqrtf(var + EPS);
    }
}

__global__ __launch_bounds__(256)
void mbn_pass2(const float* __restrict__ x, float* __restrict__ out,
               const float* __restrict__ inv, const unsigned* __restrict__ dirtyCnt,
               const int* __restrict__ dirtyLoc, const int* __restrict__ padArr) {
    // 8192 blocks x 2048 float4: each block's chunk lies in ONE channel plane
    const int blk = blockIdx.x;
    const float sc = inv[(blk >> 3) & 63];             // 8 blocks per plane
    const f32x4* x4 = (const f32x4*)x;
    f32x4* out4 = (f32x4*)out;
    const size_t base = (size_t)blk * 2048 + threadIdx.x;
#pragma unroll
    for (int k = 0; k < 8; ++k) {
        size_t i = base + (size_t)k * 256;
        f32x4 v = x4[i];
        v *= sc;
        __builtin_nontemporal_store(v, &out4[i]);      // out never re-read
    }

    // folded fixup: each block patches only its OWN float range (no cross-
    // block ordering needed). dirtyCnt == 0 in practice -> uniform early out.
    unsigned cnt = *dirtyCnt;
    if (cnt != 0) {
        __syncthreads();                               // order NT stores vs patch
        if (threadIdx.x == 0) {
            if (cnt > DIRTY_CAP) cnt = DIRTY_CAP;
            const int bb = blk >> 9, cc = (blk >> 3) & 63, seg = blk & 7;
            const int lo = seg * 8192, hi = lo + 8192;
            for (unsigned i = 0; i < cnt; ++i) {
                int loc = dirtyLoc[i];
                int b = loc >> 16, wh = loc & 65535;
                if (b != bb || wh < lo || wh >= hi) continue;
                if (wh == 0 && padArr[b] > 0) continue;   // (0,0) override wins
                size_t idx = (((size_t)(b * 64 + cc)) << 16) + wh;
                out[idx] = x[idx];                        // m=0 w/ nonzero x: out = x
            }
        }
    }
}

extern "C" void kernel_launch(void* const* d_in, const int* in_sizes, int n_in,
                              void* d_out, int out_size, void* d_ws, size_t ws_size,
                              hipStream_t stream) {
    const float* x = (const float*)d_in[0];
    float* out = (float*)d_out;
    float* wsf = (float*)d_ws;

    float*    sqPart   = wsf;
    unsigned* nPart    = (unsigned*)(wsf + 131072);
    unsigned* dirtyCnt = (unsigned*)(wsf + 147456);
    float*    inv      = wsf + 147520;
    int*      padArr   = (int*)(wsf + 147584);
    int*      dirtyLoc = (int*)(wsf + 147600);

    // only dirtyCnt needs zeroing (partials are written unconditionally)
    hipMemsetAsync((char*)d_ws + 147456 * 4, 0, 64, stream);

    mbn_pass1<<<GRID1, 512, 0, stream>>>(x, sqPart, nPart, dirtyCnt, dirtyLoc);
    mbn_finalize<<<1, 1024, 0, stream>>>(x, sqPart, nPart, dirtyCnt, dirtyLoc, inv, padArr);
    mbn_pass2<<<8192, 256, 0, stream>>>(x, out, inv, dirtyCnt, dirtyLoc, padArr);
}